// Round 1
// baseline (551.290 us; speedup 1.0000x reference)
//
#include <hip/hip_runtime.h>
#include <math.h>

#define D 128

__device__ __forceinline__ float4 ld4(const float* p) { return *(const float4*)p; }

// ---------------- degree counting ----------------
__global__ void count_kernel(const int* __restrict__ src, const int* __restrict__ dst,
                             int* __restrict__ cnt_src, int* __restrict__ cnt_dst, int E) {
  int i = blockIdx.x * blockDim.x + threadIdx.x;
  int stride = gridDim.x * blockDim.x;
  for (; i < E; i += stride) {
    atomicAdd(&cnt_src[src[i]], 1);
    atomicAdd(&cnt_dst[dst[i]], 1);
  }
}

// ---------------- scan: row_ptr/cursor + dinv ----------------
__global__ __launch_bounds__(256) void scan_kernel(
    const int* __restrict__ cnt_src, const int* __restrict__ cnt_dst,
    float* __restrict__ dinv, int* __restrict__ row_ptr, int* __restrict__ cursor, int N) {
  __shared__ int part[256];
  int t = threadIdx.x;
  int chunk = (N + 255) / 256;
  int base = t * chunk;
  int sum = 0;
  for (int i = 0; i < chunk; ++i) {
    int idx = base + i;
    if (idx < N) sum += cnt_dst[idx];
  }
  part[t] = sum;
  __syncthreads();
  if (t == 0) {
    int run = 0;
    for (int i = 0; i < 256; ++i) { int v = part[i]; part[i] = run; run += v; }
  }
  __syncthreads();
  int run = part[t];
  for (int i = 0; i < chunk; ++i) {
    int idx = base + i;
    if (idx < N) {
      int v = cnt_dst[idx];
      row_ptr[idx] = run; cursor[idx] = run; run += v;
      int dg = cnt_src[idx];
      dinv[idx] = dg > 0 ? rsqrtf((float)dg) : 0.f;
    }
  }
  if (t == 255) row_ptr[N] = run;
}

// ---------------- CSR scatter ----------------
__global__ void scatter_kernel(const int* __restrict__ src, const int* __restrict__ dst,
                               int* __restrict__ cursor, int* __restrict__ csr_src, int E) {
  int i = blockIdx.x * blockDim.x + threadIdx.x;
  int stride = gridDim.x * blockDim.x;
  for (; i < E; i += stride) {
    int pos = atomicAdd(&cursor[dst[i]], 1);
    csr_src[pos] = src[i];
  }
}

// ---------------- GCN aggregation (block per dst node) ----------------
__global__ __launch_bounds__(128) void agg_kernel(
    const float* __restrict__ feats, const float* __restrict__ dinv,
    const int* __restrict__ row_ptr, const int* __restrict__ csr_src,
    float* __restrict__ out) {
  __shared__ int idx[128];
  __shared__ float dv[128];
  int n = blockIdx.x, f = threadIdx.x;
  int beg = row_ptr[n], end = row_ptr[n + 1];
  float acc = 0.f;
  for (int c = beg; c < end; c += 128) {
    int j = c + f;
    if (j < end) { int s = csr_src[j]; idx[f] = s; dv[f] = dinv[s]; }
    __syncthreads();
    int cnt = min(128, end - c);
    for (int u = 0; u < cnt; ++u)
      acc += feats[idx[u] * D + f] * dv[u];
    __syncthreads();
  }
  out[n * D + f] = acc * dinv[n];
}

// ---------------- generic fp32 GEMM: C = act(A1@W1^T [+ A2@W2^T] + b1 [+ b2] [+ R]) ----------------
// A: M x 128, W: 128 x 128 row-major, C: M x 128. grid = M/32, block = 256.
__global__ __launch_bounds__(256) void gemm128_kernel(
    const float* __restrict__ A1, const float* __restrict__ W1, const float* __restrict__ b1,
    const float* __restrict__ A2, const float* __restrict__ W2, const float* __restrict__ b2,
    const float* __restrict__ Rres, float* __restrict__ C, int act) {
  __shared__ float As[32][36];
  __shared__ float Ws[32][132];
  const int t = threadIdx.x;
  const int m0 = blockIdx.x * 32;
  const int tr = t >> 5, tc = t & 31;
  float acc[4][4] = {};
  for (int pair = 0; pair < 2; ++pair) {
    const float* A = pair ? A2 : A1;
    const float* W = pair ? W2 : W1;
    if (A == nullptr) break;
    for (int kc = 0; kc < 128; kc += 32) {
      __syncthreads();
      {
        int r = t >> 3, kq = t & 7;
        float4 v = ld4(&A[(m0 + r) * D + kc + kq * 4]);
        As[kq * 4 + 0][r] = v.x; As[kq * 4 + 1][r] = v.y;
        As[kq * 4 + 2][r] = v.z; As[kq * 4 + 3][r] = v.w;
      }
      for (int i = 0; i < 4; ++i) {
        int id = t + i * 256; int n = id >> 3, kq = id & 7;
        float4 v = ld4(&W[n * D + kc + kq * 4]);
        Ws[kq * 4 + 0][n] = v.x; Ws[kq * 4 + 1][n] = v.y;
        Ws[kq * 4 + 2][n] = v.z; Ws[kq * 4 + 3][n] = v.w;
      }
      __syncthreads();
#pragma unroll
      for (int kd = 0; kd < 32; ++kd) {
        float4 a = *(const float4*)&As[kd][tr * 4];
        float4 w = *(const float4*)&Ws[kd][tc * 4];
        float aa[4] = {a.x, a.y, a.z, a.w};
        float ww[4] = {w.x, w.y, w.z, w.w};
#pragma unroll
        for (int i = 0; i < 4; ++i)
#pragma unroll
          for (int j = 0; j < 4; ++j) acc[i][j] += aa[i] * ww[j];
      }
    }
  }
  float bias[4] = {0.f, 0.f, 0.f, 0.f};
  if (b1) { float4 bb = ld4(&b1[tc * 4]); bias[0] += bb.x; bias[1] += bb.y; bias[2] += bb.z; bias[3] += bb.w; }
  if (b2) { float4 bb = ld4(&b2[tc * 4]); bias[0] += bb.x; bias[1] += bb.y; bias[2] += bb.z; bias[3] += bb.w; }
#pragma unroll
  for (int i = 0; i < 4; ++i) {
    int m = m0 + tr * 4 + i;
    float v[4];
#pragma unroll
    for (int j = 0; j < 4; ++j) v[j] = acc[i][j] + bias[j];
    if (Rres) {
      float4 rr = ld4(&Rres[m * D + tc * 4]);
      v[0] += rr.x; v[1] += rr.y; v[2] += rr.z; v[3] += rr.w;
    }
    if (act) {
#pragma unroll
      for (int j = 0; j < 4; ++j) v[j] = fmaxf(v[j], 0.f);
    }
    float4 ov = {v[0], v[1], v[2], v[3]};
    *(float4*)&C[m * D + tc * 4] = ov;
  }
}

// ---------------- flash attention (fp32, 4 heads of 32, online softmax) ----------------
// block = 256 threads, covers 32 q-rows, all heads; chunks of 32 keys.
__global__ __launch_bounds__(256) void flash_kernel(
    const float* __restrict__ Q, const float* __restrict__ Kb, const float* __restrict__ Vb,
    float* __restrict__ O, int Slen) {
  __shared__ float Qs[128 * 36];      // [d][r], d-major
  __shared__ float KPs[4672];         // union: Ks [d][33] (4224) / Ps h*1156 + s*36 + r (4616)
  __shared__ float Vs[32 * 132];      // [s][d]
  __shared__ float red[4 * 32 * 9];
  __shared__ float m_s[128], l_s[128], a_s[128];

  const int t = threadIdx.x;
  const int n0 = blockIdx.x * 32;
  const int g1_h = t >> 6, g1_rg = (t >> 3) & 7, g1_sg = t & 7;
  const int pv_rg = t >> 5, pv_dg = t & 31, pv_h = pv_dg >> 3;

  for (int i = 0; i < 4; ++i) {
    int id = t + i * 256; int r = id >> 5, dq = id & 31;
    float4 v = ld4(&Q[(n0 + r) * D + dq * 4]);
    Qs[(dq * 4 + 0) * 36 + r] = v.x; Qs[(dq * 4 + 1) * 36 + r] = v.y;
    Qs[(dq * 4 + 2) * 36 + r] = v.z; Qs[(dq * 4 + 3) * 36 + r] = v.w;
  }
  if (t < 128) { m_s[t] = -1e30f; l_s[t] = 0.f; }
  float o[4][4] = {};
  __syncthreads();

  for (int c = 0; c < Slen; c += 32) {
    for (int i = 0; i < 4; ++i) {
      int id = t + i * 256; int s = id >> 5, dq = id & 31;
      float4 kv = ld4(&Kb[(c + s) * D + dq * 4]);
      KPs[(dq * 4 + 0) * 33 + s] = kv.x; KPs[(dq * 4 + 1) * 33 + s] = kv.y;
      KPs[(dq * 4 + 2) * 33 + s] = kv.z; KPs[(dq * 4 + 3) * 33 + s] = kv.w;
      float4 vv = ld4(&Vb[(c + s) * D + dq * 4]);
      *(float4*)&Vs[s * 132 + dq * 4] = vv;
    }
    __syncthreads();
    // QK^T: 4 rows x 4 keys per thread, head g1_h
    float sc[4][4] = {};
#pragma unroll
    for (int kd = 0; kd < 32; ++kd) {
      int gd = g1_h * 32 + kd;
      float4 q4 = *(const float4*)&Qs[gd * 36 + g1_rg * 4];
      float qq[4] = {q4.x, q4.y, q4.z, q4.w};
      float kk[4];
#pragma unroll
      for (int j = 0; j < 4; ++j) kk[j] = KPs[gd * 33 + g1_sg * 4 + j];
#pragma unroll
      for (int i = 0; i < 4; ++i)
#pragma unroll
        for (int j = 0; j < 4; ++j) sc[i][j] += qq[i] * kk[j];
    }
    const float scale = 0.17677669529663687f; // 1/sqrt(32)
    float lm[4];
#pragma unroll
    for (int i = 0; i < 4; ++i) {
#pragma unroll
      for (int j = 0; j < 4; ++j) sc[i][j] *= scale;
      lm[i] = fmaxf(fmaxf(sc[i][0], sc[i][1]), fmaxf(sc[i][2], sc[i][3]));
      red[g1_h * 288 + (g1_rg * 4 + i) * 9 + g1_sg] = lm[i];
    }
    __syncthreads();
    if (t < 128) {
      int h = t >> 5, r = t & 31;
      float mc = red[h * 288 + r * 9 + 0];
      for (int g = 1; g < 8; ++g) mc = fmaxf(mc, red[h * 288 + r * 9 + g]);
      float mo = m_s[t], mn = fmaxf(mo, mc);
      a_s[t] = __expf(mo - mn);
      m_s[t] = mn;
    }
    __syncthreads();
    // exp, write P (overwrites Ks region -- safe: all Ks reads done before prev barrier)
#pragma unroll
    for (int i = 0; i < 4; ++i) {
      float mr = m_s[g1_h * 32 + g1_rg * 4 + i];
      float ps = 0.f;
#pragma unroll
      for (int j = 0; j < 4; ++j) {
        float p = __expf(sc[i][j] - mr);
        KPs[g1_h * 1156 + (g1_sg * 4 + j) * 36 + g1_rg * 4 + i] = p;
        ps += p;
      }
      red[g1_h * 288 + (g1_rg * 4 + i) * 9 + g1_sg] = ps;
    }
    __syncthreads();
    if (t < 128) {
      int h = t >> 5, r = t & 31;
      float ssum = 0.f;
      for (int g = 0; g < 8; ++g) ssum += red[h * 288 + r * 9 + g];
      l_s[t] = l_s[t] * a_s[t] + ssum;
    }
    // PV: 4 rows x 4 dims per thread (reads a_s, Ps, Vs; no conflict with l-update)
#pragma unroll
    for (int i = 0; i < 4; ++i) {
      float a = a_s[pv_h * 32 + pv_rg * 4 + i];
      o[i][0] *= a; o[i][1] *= a; o[i][2] *= a; o[i][3] *= a;
    }
    for (int s = 0; s < 32; ++s) {
      float4 p4 = *(const float4*)&KPs[pv_h * 1156 + s * 36 + pv_rg * 4];
      float4 v4 = *(const float4*)&Vs[s * 132 + pv_dg * 4];
      float pp[4] = {p4.x, p4.y, p4.z, p4.w};
      float vv[4] = {v4.x, v4.y, v4.z, v4.w};
#pragma unroll
      for (int i = 0; i < 4; ++i)
#pragma unroll
        for (int j = 0; j < 4; ++j) o[i][j] += pp[i] * vv[j];
    }
    __syncthreads();
  }
#pragma unroll
  for (int i = 0; i < 4; ++i) {
    float linv = 1.f / l_s[pv_h * 32 + pv_rg * 4 + i];
    float4 v = {o[i][0] * linv, o[i][1] * linv, o[i][2] * linv, o[i][3] * linv};
    *(float4*)&O[(n0 + pv_rg * 4 + i) * D + pv_dg * 4] = v;
  }
}

// ---------------- LayerNorm + L2 normalize (1 wave per row) ----------------
__global__ __launch_bounds__(64) void ln_l2_kernel(
    const float* __restrict__ X, const float* __restrict__ g, const float* __restrict__ b,
    float* __restrict__ out) {
  int n = blockIdx.x, t = threadIdx.x;
  float2 v = *(const float2*)&X[n * D + t * 2];
  float s = v.x + v.y;
  for (int off = 32; off; off >>= 1) s += __shfl_xor(s, off);
  float mu = s * (1.f / 128.f);
  float dx = v.x - mu, dy = v.y - mu;
  float q = dx * dx + dy * dy;
  for (int off = 32; off; off >>= 1) q += __shfl_xor(q, off);
  float rs = rsqrtf(q * (1.f / 128.f) + 1e-5f);
  float2 gg = *(const float2*)&g[t * 2];
  float2 bb = *(const float2*)&b[t * 2];
  float yx = dx * rs * gg.x + bb.x;
  float yy = dy * rs * gg.y + bb.y;
  float nn = yx * yx + yy * yy;
  for (int off = 32; off; off >>= 1) nn += __shfl_xor(nn, off);
  float inv = 1.f / fmaxf(sqrtf(nn), 1e-12f);
  float2 ov = {yx * inv, yy * inv};
  *(float2*)&out[n * D + t * 2] = ov;
}

// ---------------- MLP layer 2 + sigmoid (1 wave per row, 4 rows per block) ----------------
__global__ __launch_bounds__(256) void mlp2_kernel(
    const float* __restrict__ H, const float* __restrict__ w2, float* __restrict__ p, int M) {
  int row = blockIdx.x * 4 + (threadIdx.x >> 6);
  int lane = threadIdx.x & 63;
  if (row >= M) return;
  float2 h2 = *(const float2*)&H[row * D + lane * 2];
  float2 w = *(const float2*)&w2[lane * 2];
  float s = h2.x * w.x + h2.y * w.y;
  for (int off = 32; off; off >>= 1) s += __shfl_xor(s, off);
  if (lane == 0) p[row] = 1.f / (1.f + __expf(-s));
}

// ---------------- edge prediction ----------------
__global__ void pred_kernel(const float* __restrict__ p, const int* __restrict__ eli,
                            float* __restrict__ out, int K) {
  int i = blockIdx.x * blockDim.x + threadIdx.x;
  if (i < K) out[i] = p[eli[i]] * p[eli[K + i]];
}

extern "C" void kernel_launch(void* const* d_in, const int* in_sizes, int n_in,
                              void* d_out, int out_size, void* d_ws, size_t ws_size,
                              hipStream_t stream) {
  const float* x       = (const float*)d_in[0];
  const float* seq     = (const float*)d_in[1];
  const int* src       = (const int*)d_in[2];
  const int* dst       = (const int*)d_in[3];
  const int* eli       = (const int*)d_in[4];
  const float* skip_w0 = (const float*)d_in[5];
  const float* skip_b0 = (const float*)d_in[6];
  const float* msg_w0  = (const float*)d_in[7];
  const float* msg_b0  = (const float*)d_in[8];
  const float* skip_w1 = (const float*)d_in[9];
  const float* skip_b1 = (const float*)d_in[10];
  const float* msg_w1  = (const float*)d_in[11];
  const float* msg_b1  = (const float*)d_in[12];
  const float* ipw     = (const float*)d_in[13];
  const float* ipb     = (const float*)d_in[14];
  const float* opw     = (const float*)d_in[15];
  const float* opb     = (const float*)d_in[16];
  const float* ln_g    = (const float*)d_in[17];
  const float* ln_b    = (const float*)d_in[18];
  const float* w1      = (const float*)d_in[19];
  const float* w2      = (const float*)d_in[20];

  const int N  = in_sizes[0] / D;   // 8192
  const int S  = in_sizes[1] / D;   // 2048
  const int E  = in_sizes[2];       // 524288
  const int Kp = in_sizes[4] / 2;   // 100000

  float* ws   = (float*)d_ws;
  float* B0   = ws;                 // rst / attn-out
  float* B1   = B0 + (size_t)N * D; // gcn1 out / pre-LN
  float* B2   = B1 + (size_t)N * D; // gcn2 out (attention input + residual)
  float* B3   = B2 + (size_t)N * D; // q / mlp hidden
  float* KB   = B3 + (size_t)N * D;
  float* VB   = KB + (size_t)S * D;
  float* dinv = VB + (size_t)S * D;
  float* pbuf = dinv + N;
  int* cnt_src = (int*)(pbuf + N);
  int* cnt_dst = cnt_src + N;
  int* row_ptr = cnt_dst + N;       // N+1
  int* cursor  = row_ptr + (N + 1);
  int* csr_src = cursor + N;        // E

  float* pred_out = (float*)d_out;
  float* emb_out  = pred_out + Kp;

  hipMemsetAsync(cnt_src, 0, 2 * (size_t)N * sizeof(int), stream);
  count_kernel<<<512, 256, 0, stream>>>(src, dst, cnt_src, cnt_dst, E);
  scan_kernel<<<1, 256, 0, stream>>>(cnt_src, cnt_dst, dinv, row_ptr, cursor, N);
  scatter_kernel<<<512, 256, 0, stream>>>(src, dst, cursor, csr_src, E);

  // GCN layer 1: B1 = rst@msg_w0^T + msg_b0 + x@skip_w0^T + skip_b0
  agg_kernel<<<N, 128, 0, stream>>>(x, dinv, row_ptr, csr_src, B0);
  gemm128_kernel<<<N / 32, 256, 0, stream>>>(B0, msg_w0, msg_b0, x, skip_w0, skip_b0, nullptr, B1, 0);
  // GCN layer 2: B2
  agg_kernel<<<N, 128, 0, stream>>>(B1, dinv, row_ptr, csr_src, B0);
  gemm128_kernel<<<N / 32, 256, 0, stream>>>(B0, msg_w1, msg_b1, B1, skip_w1, skip_b1, nullptr, B2, 0);

  // attention projections
  gemm128_kernel<<<N / 32, 256, 0, stream>>>(B2, ipw, ipb, nullptr, nullptr, nullptr, nullptr, B3, 0);            // Q
  gemm128_kernel<<<S / 32, 256, 0, stream>>>(seq, ipw + D * D, ipb + D, nullptr, nullptr, nullptr, nullptr, KB, 0); // K
  gemm128_kernel<<<S / 32, 256, 0, stream>>>(seq, ipw + 2 * D * D, ipb + 2 * D, nullptr, nullptr, nullptr, nullptr, VB, 0); // V
  flash_kernel<<<N / 32, 256, 0, stream>>>(B3, KB, VB, B0, S);
  // out_proj + residual(B2) -> B1
  gemm128_kernel<<<N / 32, 256, 0, stream>>>(B0, opw, opb, nullptr, nullptr, nullptr, B2, B1, 0);
  // LayerNorm + L2 normalize -> node embeddings (second output)
  ln_l2_kernel<<<N, 64, 0, stream>>>(B1, ln_g, ln_b, emb_out);
  // MLP: hidden = relu(emb @ w1^T); p = sigmoid(hidden @ w2^T)
  gemm128_kernel<<<N / 32, 256, 0, stream>>>(emb_out, w1, nullptr, nullptr, nullptr, nullptr, nullptr, B3, 1);
  mlp2_kernel<<<N / 4, 256, 0, stream>>>(B3, w2, pbuf, N);
  pred_kernel<<<(Kp + 255) / 256, 256, 0, stream>>>(pbuf, eli, pred_out, Kp);
}